// Round 1
// baseline (2309.344 us; speedup 1.0000x reference)
//
#include <hip/hip_runtime.h>

#define NATOMS 300000
#define NBONDS 600000
#define MAXNB  6
#define AFD    133
#define BFD    147
#define HID    256
#define NMOLS  10000

typedef __attribute__((ext_vector_type(8))) short short8;
typedef __attribute__((ext_vector_type(4))) float f32x4;

__device__ __forceinline__ ushort f2bf(float f) {
    union { float f; unsigned u; } x; x.f = f;
    unsigned r = (x.u + 0x7FFFu + ((x.u >> 16) & 1u)) >> 16;
    return (ushort)r;
}
__device__ __forceinline__ float bf2f(ushort h) {
    union { unsigned u; float f; } x; x.u = ((unsigned)h) << 16;
    return x.f;
}

// ---------------- weight prep: fp32 [K][256] -> bf16 tiled [kc][n][64] ----------------
// tiled index = (kc*256 + n)*64 + kl ; k = kc*64 + kl
__global__ __launch_bounds__(256) void prep_w(const float* __restrict__ W,
                                              ushort* __restrict__ wt,
                                              int Ksrc, int total, int mode) {
    int gid = blockIdx.x * 256 + threadIdx.x;
    if (gid >= total) return;
    int kl = gid & 63;
    int n  = (gid >> 6) & 255;
    int kc = gid >> 14;
    int k  = kc * 64 + kl;
    float v;
    if (mode == 0) {
        v = (k < Ksrc) ? W[k * 256 + n] : 0.f;
    } else {            // W_o: rows [0,133) atom feats (padded to 192), rows [133,389) message part
        if (k < 192) v = (k < 133) ? W[k * 256 + n] : 0.f;
        else         v = W[(133 + (k - 192)) * 256 + n];
    }
    wt[gid] = f2bf(v);
}

// ---------------- neighbor gather-sum: amsg[a] = sum_nb msg[a2b[a][nb]] ----------------
__global__ __launch_bounds__(256) void gather_sum_kernel(const ushort* __restrict__ msg,
                                                         const int* __restrict__ a2b,
                                                         ushort* __restrict__ amsg) {
    int gid = blockIdx.x * 256 + threadIdx.x;   // NATOMS*32 threads exactly
    int a = gid >> 5;
    int coff = (gid & 31) * 8;
    float acc[8] = {0.f,0.f,0.f,0.f,0.f,0.f,0.f,0.f};
    const int* ab = a2b + a * 6;
#pragma unroll
    for (int nb = 0; nb < 6; ++nb) {
        int b = ab[nb];
        union { uint4 u; ushort s[8]; } v;
        v.u = *reinterpret_cast<const uint4*>(msg + (size_t)b * 256 + coff);
#pragma unroll
        for (int j = 0; j < 8; ++j) acc[j] += bf2f(v.s[j]);
    }
    union { uint4 u; ushort s[8]; } o;
#pragma unroll
    for (int j = 0; j < 8; ++j) o.s[j] = f2bf(acc[j]);
    *reinterpret_cast<uint4*>(amsg + (size_t)a * 256 + coff) = o.u;
}

// ---------------- GEMM: C[64 x 256] per block, BK=64, 4 waves, mfma 16x16x32 bf16 -----
// MODE 0: inp = f_bonds @ W_i            -> out0 = inp(bf16), out1 = relu(inp)(bf16)
// MODE 1: msg' = relu(inp + (amsg[b2a] - msg[b2revb]) @ W_h) -> out0
// MODE 2: h = relu([f_atoms|amsg] @ W_o + b_o); dot w_ffn; segment atomics
template<int MODE>
__global__ __launch_bounds__(256)
void gemm_kernel(const float* __restrict__ xf,
                 const ushort* __restrict__ amsg,
                 const ushort* __restrict__ msgin,
                 const ushort* __restrict__ inp,
                 const int* __restrict__ b2a,
                 const int* __restrict__ b2revb,
                 const ushort* __restrict__ wt,
                 ushort* __restrict__ out0,
                 ushort* __restrict__ out1,
                 const float* __restrict__ b_o,
                 const float* __restrict__ w_ffn,
                 const int* __restrict__ segids,
                 float* __restrict__ mol_acc,
                 float* __restrict__ mol_cnt,
                 int M, int nchunks)
{
    __shared__ ushort Xs[64 * 72];    // +8 pad: 144B row stride (16B aligned, 2-way banks = free)
    __shared__ ushort Ws[256 * 72];   // transposed weight tile Ws[n][k]
    __shared__ float rowpart[4][64];
    __shared__ float vals[64];
    __shared__ int   sseg[64];

    const int tid  = threadIdx.x;
    const int wave = tid >> 6;
    const int lane = tid & 63;
    const int q    = lane >> 4;
    const int l16  = lane & 15;
    const int row0 = blockIdx.x * 64;

    const int sr = tid >> 2;            // staging row 0..63 (4 threads per row)
    const int sq = (tid & 3) * 16;      // staging k-offset within chunk

    f32x4 acc[4][4];
#pragma unroll
    for (int i = 0; i < 4; ++i)
#pragma unroll
        for (int j = 0; j < 4; ++j)
            acc[i][j] = (f32x4){0.f, 0.f, 0.f, 0.f};

    int ia = 0, ir = 0;
    if (MODE == 1) { int b = row0 + sr; ia = b2a[b]; ir = b2revb[b]; }

    for (int kc = 0; kc < nchunks; ++kc) {
        // ---- stage W tile (256 n x 64 k), fully coalesced 16B chunks ----
        {
            const uint4* src = reinterpret_cast<const uint4*>(wt) + (size_t)kc * 2048;
            uint4* dst = reinterpret_cast<uint4*>(Ws);
#pragma unroll
            for (int s = 0; s < 8; ++s) {
                int c = s * 256 + tid;                 // c in [0,2048): n = c>>3, 16B chunk c&7
                dst[(c >> 3) * 9 + (c & 7)] = src[c];
            }
        }
        // ---- stage X tile (64 rows x 64 k) ----
        {
            const int k0 = kc * 64 + sq;
            union { uint4 u[2]; ushort s[16]; } hv;
            if (MODE == 0) {
                int b = row0 + sr;
                const float* p = xf + (size_t)b * BFD;
#pragma unroll
                for (int j = 0; j < 16; ++j) {
                    int k = k0 + j;
                    hv.s[j] = (k < BFD) ? f2bf(p[k]) : (ushort)0;
                }
            } else if (MODE == 1) {
                union { uint4 u[2]; ushort s[16]; } am, mm;
                const uint4* pa = reinterpret_cast<const uint4*>(amsg  + (size_t)ia * 256 + k0);
                const uint4* pm = reinterpret_cast<const uint4*>(msgin + (size_t)ir * 256 + k0);
                am.u[0] = pa[0]; am.u[1] = pa[1];
                mm.u[0] = pm[0]; mm.u[1] = pm[1];
#pragma unroll
                for (int j = 0; j < 16; ++j)
                    hv.s[j] = f2bf(bf2f(am.s[j]) - bf2f(mm.s[j]));
            } else {
                int a = row0 + sr;
                if (a >= M) {
#pragma unroll
                    for (int j = 0; j < 16; ++j) hv.s[j] = 0;
                } else if (k0 >= 192) {
                    const uint4* pa = reinterpret_cast<const uint4*>(amsg + (size_t)a * 256 + (k0 - 192));
                    hv.u[0] = pa[0]; hv.u[1] = pa[1];
                } else {
                    const float* p = xf + (size_t)a * AFD;
#pragma unroll
                    for (int j = 0; j < 16; ++j) {
                        int k = k0 + j;
                        hv.s[j] = (k < AFD) ? f2bf(p[k]) : (ushort)0;
                    }
                }
            }
            uint4* xdst = reinterpret_cast<uint4*>(Xs) + sr * 9 + (tid & 3) * 2;
            xdst[0] = hv.u[0];
            xdst[1] = hv.u[1];
        }
        __syncthreads();

        // ---- MFMA: 2 k-steps of 32, wave covers cols [wave*64, wave*64+64) ----
        const uint4* Xs4 = reinterpret_cast<const uint4*>(Xs);
        const uint4* Ws4 = reinterpret_cast<const uint4*>(Ws);
#pragma unroll
        for (int ks = 0; ks < 2; ++ks) {
            short8 af[4], bfr[4];
#pragma unroll
            for (int mt = 0; mt < 4; ++mt) {
                union { uint4 u; short8 s; } t;
                t.u = Xs4[(mt * 16 + l16) * 9 + ks * 4 + q];   // A[m=l16][k=q*8+j]
                af[mt] = t.s;
            }
#pragma unroll
            for (int nt = 0; nt < 4; ++nt) {
                int n = wave * 64 + nt * 16 + l16;
                union { uint4 u; short8 s; } t;
                t.u = Ws4[n * 9 + ks * 4 + q];                 // B[k=q*8+j][n=l16]
                bfr[nt] = t.s;
            }
#pragma unroll
            for (int mt = 0; mt < 4; ++mt)
#pragma unroll
                for (int nt = 0; nt < 4; ++nt)
                    acc[mt][nt] = __builtin_amdgcn_mfma_f32_16x16x32_bf16(
                        af[mt], bfr[nt], acc[mt][nt], 0, 0, 0);
        }
        __syncthreads();
    }

    // ---- epilogue ----  C/D: col = l16, row = q*4 + reg (within 16x16 tile)
    if (MODE == 0) {
#pragma unroll
        for (int mt = 0; mt < 4; ++mt)
#pragma unroll
            for (int rr = 0; rr < 4; ++rr) {
                int grow = row0 + mt * 16 + q * 4 + rr;
#pragma unroll
                for (int nt = 0; nt < 4; ++nt) {
                    int gcol = wave * 64 + nt * 16 + l16;
                    size_t idx = (size_t)grow * 256 + gcol;
                    float v = acc[mt][nt][rr];
                    out0[idx] = f2bf(v);
                    out1[idx] = f2bf(fmaxf(v, 0.f));
                }
            }
    } else if (MODE == 1) {
#pragma unroll
        for (int mt = 0; mt < 4; ++mt)
#pragma unroll
            for (int rr = 0; rr < 4; ++rr) {
                int grow = row0 + mt * 16 + q * 4 + rr;
#pragma unroll
                for (int nt = 0; nt < 4; ++nt) {
                    int gcol = wave * 64 + nt * 16 + l16;
                    size_t idx = (size_t)grow * 256 + gcol;
                    float v = acc[mt][nt][rr] + bf2f(inp[idx]);
                    out0[idx] = f2bf(fmaxf(v, 0.f));
                }
            }
    } else {
        float bo4[4], wf4[4];
#pragma unroll
        for (int nt = 0; nt < 4; ++nt) {
            int gcol = wave * 64 + nt * 16 + l16;
            bo4[nt] = b_o[gcol];
            wf4[nt] = w_ffn[gcol];
        }
#pragma unroll
        for (int mt = 0; mt < 4; ++mt)
#pragma unroll
            for (int rr = 0; rr < 4; ++rr) {
                float s = 0.f;
#pragma unroll
                for (int nt = 0; nt < 4; ++nt) {
                    float h = fmaxf(acc[mt][nt][rr] + bo4[nt], 0.f);
                    s = fmaf(h, wf4[nt], s);
                }
#pragma unroll
                for (int off = 1; off < 16; off <<= 1)
                    s += __shfl_xor(s, off, 64);
                if (l16 == 0) rowpart[wave][mt * 16 + q * 4 + rr] = s;
            }
        __syncthreads();
        if (tid < 64) {
            int a = row0 + tid;
            vals[tid] = rowpart[0][tid] + rowpart[1][tid] + rowpart[2][tid] + rowpart[3][tid];
            sseg[tid] = (a < M) ? segids[a] : -1;
        }
        __syncthreads();
        if (tid < 64) {
            int myseg = sseg[tid];
            bool leader = (myseg >= 0) && (tid == 0 || sseg[tid - 1] != myseg);
            if (leader) {
                float sum = 0.f; int cnt = 0;
                for (int rr = tid; rr < 64 && sseg[rr] == myseg; ++rr) { sum += vals[rr]; ++cnt; }
                atomicAdd(mol_acc + myseg, sum);
                atomicAdd(mol_cnt + myseg, (float)cnt);
            }
        }
    }
}

// ---------------- final: out[m] = mol_acc[m]/max(cnt,1) + b_ffn ----------------
__global__ __launch_bounds__(256) void finalize_kernel(const float* __restrict__ mol_acc,
                                                       const float* __restrict__ mol_cnt,
                                                       const float* __restrict__ b_ffn,
                                                       float* __restrict__ out) {
    int m = blockIdx.x * 256 + threadIdx.x;
    if (m < NMOLS)
        out[m] = mol_acc[m] / fmaxf(mol_cnt[m], 1.f) + b_ffn[0];
}

extern "C" void kernel_launch(void* const* d_in, const int* in_sizes, int n_in,
                              void* d_out, int out_size, void* d_ws, size_t ws_size,
                              hipStream_t stream) {
    const float* f_atoms = (const float*)d_in[0];
    const float* f_bonds = (const float*)d_in[1];
    const float* W_i     = (const float*)d_in[2];
    const float* W_h     = (const float*)d_in[3];
    const float* W_o     = (const float*)d_in[4];
    const float* b_o     = (const float*)d_in[5];
    const float* W_ffn   = (const float*)d_in[6];
    const float* b_ffn   = (const float*)d_in[7];
    const int* a2b       = (const int*)d_in[8];
    const int* b2a       = (const int*)d_in[9];
    const int* b2revb    = (const int*)d_in[10];
    const int* segids    = (const int*)d_in[11];
    float* out = (float*)d_out;

    char* ws = (char*)d_ws;
    size_t off = 0;
    ushort* inp  = (ushort*)(ws + off); off += (size_t)NBONDS * 256 * 2;   // 307.2 MB
    ushort* msgA = (ushort*)(ws + off); off += (size_t)NBONDS * 256 * 2;
    ushort* msgB = (ushort*)(ws + off); off += (size_t)NBONDS * 256 * 2;
    ushort* amsg = (ushort*)(ws + off); off += (size_t)NATOMS * 256 * 2;   // 153.6 MB
    ushort* wi_t = (ushort*)(ws + off); off += (size_t)192 * 256 * 2;
    ushort* wh_t = (ushort*)(ws + off); off += (size_t)256 * 256 * 2;
    ushort* wo_t = (ushort*)(ws + off); off += (size_t)448 * 256 * 2;
    float* mol_acc = (float*)(ws + off); off += (size_t)NMOLS * 4;
    float* mol_cnt = (float*)(ws + off); off += (size_t)NMOLS * 4;

    // weight prep (tiny)
    prep_w<<<(192 * 256 + 255) / 256, 256, 0, stream>>>(W_i, wi_t, BFD, 192 * 256, 0);
    prep_w<<<(256 * 256 + 255) / 256, 256, 0, stream>>>(W_h, wh_t, 256, 256 * 256, 0);
    prep_w<<<(448 * 256 + 255) / 256, 256, 0, stream>>>(W_o, wo_t, 133, 448 * 256, 1);

    // inp = f_bonds @ W_i ; msgA = relu(inp)
    gemm_kernel<0><<<NBONDS / 64, 256, 0, stream>>>(
        f_bonds, nullptr, nullptr, nullptr, nullptr, nullptr, wi_t,
        inp, msgA, nullptr, nullptr, nullptr, nullptr, nullptr, NBONDS, 3);

    ushort* cur = msgA; ushort* nxt = msgB;
    for (int d = 0; d < 2; ++d) {
        gather_sum_kernel<<<NATOMS * 32 / 256, 256, 0, stream>>>(cur, a2b, amsg);
        gemm_kernel<1><<<NBONDS / 64, 256, 0, stream>>>(
            nullptr, amsg, cur, inp, b2a, b2revb, wh_t,
            nxt, nullptr, nullptr, nullptr, nullptr, nullptr, nullptr, NBONDS, 4);
        ushort* t = cur; cur = nxt; nxt = t;
    }
    gather_sum_kernel<<<NATOMS * 32 / 256, 256, 0, stream>>>(cur, a2b, amsg);

    hipMemsetAsync(mol_acc, 0, (size_t)NMOLS * 2 * 4, stream);

    gemm_kernel<2><<<(NATOMS + 63) / 64, 256, 0, stream>>>(
        f_atoms, amsg, nullptr, nullptr, nullptr, nullptr, wo_t,
        nullptr, nullptr, b_o, W_ffn, segids, mol_acc, mol_cnt, NATOMS, 7);

    finalize_kernel<<<(NMOLS + 255) / 256, 256, 0, stream>>>(mol_acc, mol_cnt, b_ffn, out);
}

// Round 2
// 2155.584 us; speedup vs baseline: 1.0713x; 1.0713x over previous
//
#include <hip/hip_runtime.h>

#define NATOMS 300000
#define NBONDS 600000
#define AFD    133
#define BFD    147
#define NMOLS  10000

typedef __attribute__((ext_vector_type(8))) short short8;
typedef __attribute__((ext_vector_type(4))) float f32x4;

__device__ __forceinline__ ushort f2bf(float f) {
    union { float f; unsigned u; } x; x.f = f;
    unsigned r = (x.u + 0x7FFFu + ((x.u >> 16) & 1u)) >> 16;
    return (ushort)r;
}
__device__ __forceinline__ float bf2f(ushort h) {
    union { unsigned u; float f; } x; x.u = ((unsigned)h) << 16;
    return x.f;
}
// pack two f32 (truncated) into one dword of two bf16: [hi f1 | lo f0]
__device__ __forceinline__ unsigned pack_bf(float f0, float f1) {
    return __builtin_amdgcn_perm(__float_as_uint(f1), __float_as_uint(f0), 0x07060302u);
}
// (a - m) per bf16 pair, optional relu on m; truncating pack
template<bool RELUM>
__device__ __forceinline__ unsigned bfpair_sub(unsigned a, unsigned m) {
    float al = __uint_as_float(a << 16), ah = __uint_as_float(a & 0xFFFF0000u);
    float ml = __uint_as_float(m << 16), mh = __uint_as_float(m & 0xFFFF0000u);
    if (RELUM) { ml = fmaxf(ml, 0.f); mh = fmaxf(mh, 0.f); }
    return pack_bf(al - ml, ah - mh);
}

// ---------- weight prep: fp32 [K][256] -> bf16 frag-major ----------
// wt[(((ks*16)+ncb)*64 + lane)*8 + j] = W[k = ks*32 + (lane>>4)*8 + j][n = ncb*16 + (lane&15)]
__global__ __launch_bounds__(256) void prep_w2(const float* __restrict__ W,
                                               ushort* __restrict__ wt,
                                               int KS, int Ksrc, int mode) {
    int gid = blockIdx.x * 256 + threadIdx.x;
    if (gid >= KS * 1024) return;
    int lane = gid & 63;
    int ncb  = (gid >> 6) & 15;
    int ks   = gid >> 10;
    int n  = ncb * 16 + (lane & 15);
    int k0 = ks * 32 + (lane >> 4) * 8;
#pragma unroll
    for (int j = 0; j < 8; ++j) {
        int k = k0 + j;
        float v;
        if (mode == 0) {
            v = (k < Ksrc) ? W[k * 256 + n] : 0.f;
        } else {    // W_o: k<133 atom part, [133,192) pad, >=192 message part
            if (k < 192) v = (k < 133) ? W[k * 256 + n] : 0.f;
            else         v = W[(133 + (k - 192)) * 256 + n];
        }
        wt[(size_t)gid * 8 + j] = f2bf(v);
    }
}

// ---------- neighbor gather-sum ----------
template<bool RELU>
__global__ __launch_bounds__(256) void gather_sum_kernel(const ushort* __restrict__ msg,
                                                         const int* __restrict__ a2b,
                                                         ushort* __restrict__ amsg) {
    int gid = blockIdx.x * 256 + threadIdx.x;
    int a = gid >> 5;
    int coff = (gid & 31) * 8;
    float acc[8] = {0.f,0.f,0.f,0.f,0.f,0.f,0.f,0.f};
    const int* ab = a2b + a * 6;
#pragma unroll
    for (int nb = 0; nb < 6; ++nb) {
        int b = ab[nb];
        union { uint4 u; ushort s[8]; } v;
        v.u = *reinterpret_cast<const uint4*>(msg + (size_t)b * 256 + coff);
#pragma unroll
        for (int j = 0; j < 8; ++j) {
            float t = bf2f(v.s[j]);
            if (RELU) t = fmaxf(t, 0.f);
            acc[j] += t;
        }
    }
    union { uint4 u; ushort s[8]; } o;
#pragma unroll
    for (int j = 0; j < 8; ++j) o.s[j] = f2bf(acc[j]);
    *reinterpret_cast<uint4*>(amsg + (size_t)a * 256 + coff) = o.u;
}

// ---------- barrier-free, LDS-free GEMM ----------
// Block: 256 thr / 4 waves. Wave = 64 rows x 128 cols. Grid: (2 col-halves, rowblocks).
// B-frags loaded straight from global (frag-major, L2-hot). A-frags per-lane gathers.
// MODE 0: inp = f_bonds @ W_i                       (fp32 rows, K=147 pad->160, 5 ks)
// MODE 1: msg' = relu(inp + (amsg[b2a] - src[b2revb]) @ W_h)   (8 ks; RELUSRC => src=relu(inp))
// MODE 2: h = relu([f_atoms|amsg] @ W_o + b_o); dot w_ffn; segment atomics (14 ks, skip ks=5)
template<int MODE, bool RELUSRC>
__global__ __launch_bounds__(256, 2)
void gemm_v2(const float* __restrict__ xf,
             const ushort* __restrict__ amsg,
             const ushort* __restrict__ msgin,
             const ushort* __restrict__ inp,
             const int* __restrict__ b2a,
             const int* __restrict__ b2revb,
             const ushort* __restrict__ wt,
             ushort* __restrict__ out0,
             const float* __restrict__ b_o,
             const float* __restrict__ w_ffn,
             const int* __restrict__ segids,
             float* __restrict__ mol_acc,
             float* __restrict__ mol_cnt,
             int M)
{
    __shared__ float svals[4][64];
    __shared__ int   sseg[4][64];

    const int tid  = threadIdx.x;
    const int wave = tid >> 6;
    const int lane = tid & 63;
    const int q    = lane >> 4;
    const int l16  = lane & 15;
    const int half = blockIdx.x;              // 0/1 -> cols [0,128) / [128,256)
    const int rb   = blockIdx.y;
    const int rowbase = rb * 256 + wave * 64;
    const int colbase = half * 128;

    f32x4 acc[4][8];
#pragma unroll
    for (int i = 0; i < 4; ++i)
#pragma unroll
        for (int j = 0; j < 8; ++j)
            acc[i][j] = (f32x4){0.f,0.f,0.f,0.f};

    // per-lane row indices (lane l16 owns row mt*16+l16 for all q)
    int rc[4], ia[4], ir[4];
#pragma unroll
    for (int mt = 0; mt < 4; ++mt) {
        int r = rowbase + mt * 16 + l16;
        rc[mt] = (r < M) ? r : (M - 1);
        if (MODE == 1) { ia[mt] = b2a[rc[mt]]; ir[mt] = b2revb[rc[mt]]; }
    }

    constexpr int NKS = (MODE == 0) ? 5 : (MODE == 1 ? 8 : 14);

#pragma unroll
    for (int ks = 0; ks < NKS; ++ks) {
        if (MODE == 2 && ks == 5) continue;   // zero rows of padded W_o

        // B-frags: global, frag-major, fully coalesced (1KB/wave/load), L2-hot
        union { uint4 u; short8 s; } bfr[8];
#pragma unroll
        for (int nt = 0; nt < 8; ++nt) {
            int ncb = half * 8 + nt;
            bfr[nt].u = *reinterpret_cast<const uint4*>(wt + ((size_t)(ks * 16 + ncb) * 64 + lane) * 8);
        }

        // A-frags: lane (q,l16) reads 16B of row rc[mt] at k-offset ks*32+q*8
        union { uint4 u; short8 s; } afr[4];
#pragma unroll
        for (int mt = 0; mt < 4; ++mt) {
            if (MODE == 1) {
                uint4 a = *reinterpret_cast<const uint4*>(amsg  + (size_t)ia[mt] * 256 + ks * 32 + q * 8);
                uint4 m = *reinterpret_cast<const uint4*>(msgin + (size_t)ir[mt] * 256 + ks * 32 + q * 8);
                afr[mt].u.x = bfpair_sub<RELUSRC>(a.x, m.x);
                afr[mt].u.y = bfpair_sub<RELUSRC>(a.y, m.y);
                afr[mt].u.z = bfpair_sub<RELUSRC>(a.z, m.z);
                afr[mt].u.w = bfpair_sub<RELUSRC>(a.w, m.w);
            } else if (MODE == 2 && ks >= 6) {
                afr[mt].u = *reinterpret_cast<const uint4*>(amsg + (size_t)rc[mt] * 256 + (ks - 6) * 32 + q * 8);
            } else {
                const int FD = (MODE == 0) ? BFD : AFD;
                const float* p = xf + (size_t)rc[mt] * FD + ks * 32 + q * 8;
                float v[8];
#pragma unroll
                for (int j = 0; j < 8; ++j) {
                    int k = ks * 32 + q * 8 + j;
                    v[j] = (k < FD) ? p[j] : 0.f;
                }
                afr[mt].u.x = pack_bf(v[0], v[1]);
                afr[mt].u.y = pack_bf(v[2], v[3]);
                afr[mt].u.z = pack_bf(v[4], v[5]);
                afr[mt].u.w = pack_bf(v[6], v[7]);
            }
        }

#pragma unroll
        for (int mt = 0; mt < 4; ++mt)
#pragma unroll
            for (int nt = 0; nt < 8; ++nt)
                acc[mt][nt] = __builtin_amdgcn_mfma_f32_16x16x32_bf16(
                    afr[mt].s, bfr[nt].s, acc[mt][nt], 0, 0, 0);
    }

    // ---- epilogue ----  C/D: col = l16 (within 16), row = q*4 + rr
    if (MODE == 0) {
#pragma unroll
        for (int mt = 0; mt < 4; ++mt)
#pragma unroll
            for (int rr = 0; rr < 4; ++rr) {
                int grow = rowbase + mt * 16 + q * 4 + rr;
                if (grow >= M) continue;
#pragma unroll
                for (int nt = 0; nt < 8; ++nt) {
                    int gcol = colbase + nt * 16 + l16;
                    out0[(size_t)grow * 256 + gcol] = f2bf(acc[mt][nt][rr]);
                }
            }
    } else if (MODE == 1) {
#pragma unroll
        for (int mt = 0; mt < 4; ++mt)
#pragma unroll
            for (int rr = 0; rr < 4; ++rr) {
                int grow = rowbase + mt * 16 + q * 4 + rr;
                if (grow >= M) continue;
#pragma unroll
                for (int nt = 0; nt < 8; ++nt) {
                    int gcol = colbase + nt * 16 + l16;
                    size_t idx = (size_t)grow * 256 + gcol;
                    float v = acc[mt][nt][rr] + bf2f(inp[idx]);
                    out0[idx] = f2bf(fmaxf(v, 0.f));
                }
            }
    } else {
        float bo[8], wf[8];
#pragma unroll
        for (int nt = 0; nt < 8; ++nt) {
            int gcol = colbase + nt * 16 + l16;
            bo[nt] = b_o[gcol];
            wf[nt] = w_ffn[gcol];
        }
#pragma unroll
        for (int mt = 0; mt < 4; ++mt)
#pragma unroll
            for (int rr = 0; rr < 4; ++rr) {
                float s = 0.f;
#pragma unroll
                for (int nt = 0; nt < 8; ++nt) {
                    float h = fmaxf(acc[mt][nt][rr] + bo[nt], 0.f);
                    s = fmaf(h, wf[nt], s);
                }
#pragma unroll
                for (int off = 1; off < 16; off <<= 1)
                    s += __shfl_xor(s, off, 64);
                if (l16 == 0) svals[wave][mt * 16 + q * 4 + rr] = s;
            }
        {
            int rl = lane;
            int grow = rb * 256 + wave * 64 + rl;
            sseg[wave][rl] = (grow < M) ? segids[grow] : -1;
        }
        __syncthreads();
        {
            int w = tid >> 6, rl = tid & 63;
            int myseg = sseg[w][rl];
            bool leader = (myseg >= 0) && (rl == 0 || sseg[w][rl - 1] != myseg);
            if (leader) {
                float sum = 0.f; int cnt = 0;
                for (int j = rl; j < 64 && sseg[w][j] == myseg; ++j) { sum += svals[w][j]; ++cnt; }
                atomicAdd(mol_acc + myseg, sum);
                if (half == 0) atomicAdd(mol_cnt + myseg, (float)cnt);
            }
        }
    }
}

__global__ __launch_bounds__(256) void finalize_kernel(const float* __restrict__ mol_acc,
                                                       const float* __restrict__ mol_cnt,
                                                       const float* __restrict__ b_ffn,
                                                       float* __restrict__ out) {
    int m = blockIdx.x * 256 + threadIdx.x;
    if (m < NMOLS)
        out[m] = mol_acc[m] / fmaxf(mol_cnt[m], 1.f) + b_ffn[0];
}

extern "C" void kernel_launch(void* const* d_in, const int* in_sizes, int n_in,
                              void* d_out, int out_size, void* d_ws, size_t ws_size,
                              hipStream_t stream) {
    const float* f_atoms = (const float*)d_in[0];
    const float* f_bonds = (const float*)d_in[1];
    const float* W_i     = (const float*)d_in[2];
    const float* W_h     = (const float*)d_in[3];
    const float* W_o     = (const float*)d_in[4];
    const float* b_o     = (const float*)d_in[5];
    const float* W_ffn   = (const float*)d_in[6];
    const float* b_ffn   = (const float*)d_in[7];
    const int* a2b       = (const int*)d_in[8];
    const int* b2a       = (const int*)d_in[9];
    const int* b2revb    = (const int*)d_in[10];
    const int* segids    = (const int*)d_in[11];
    float* out = (float*)d_out;

    char* ws = (char*)d_ws;
    size_t off = 0;
    // pad row counts to block multiples (256) so clamped reads stay in-buffer
    ushort* inp  = (ushort*)(ws + off); off += (size_t)600064 * 256 * 2;
    ushort* msg1 = (ushort*)(ws + off); off += (size_t)600064 * 256 * 2;
    ushort* msg2 = (ushort*)(ws + off); off += (size_t)600064 * 256 * 2;
    ushort* amsg = (ushort*)(ws + off); off += (size_t)NATOMS * 256 * 2;
    ushort* wi_t = (ushort*)(ws + off); off += (size_t)5  * 1024 * 8 * 2;
    ushort* wh_t = (ushort*)(ws + off); off += (size_t)8  * 1024 * 8 * 2;
    ushort* wo_t = (ushort*)(ws + off); off += (size_t)14 * 1024 * 8 * 2;
    float* mol_acc = (float*)(ws + off); off += (size_t)NMOLS * 4;
    float* mol_cnt = (float*)(ws + off); off += (size_t)NMOLS * 4;

    prep_w2<<<(5  * 1024 + 255) / 256, 256, 0, stream>>>(W_i, wi_t, 5,  BFD, 0);
    prep_w2<<<(8  * 1024 + 255) / 256, 256, 0, stream>>>(W_h, wh_t, 8,  256, 0);
    prep_w2<<<(14 * 1024 + 255) / 256, 256, 0, stream>>>(W_o, wo_t, 14, 133, 1);

    // inp = f_bonds @ W_i   (msg0 = relu(inp) is applied inline downstream)
    gemm_v2<0, false><<<dim3(2, 2344), 256, 0, stream>>>(
        f_bonds, nullptr, nullptr, nullptr, nullptr, nullptr, wi_t,
        inp, nullptr, nullptr, nullptr, nullptr, nullptr, NBONDS);

    // depth iter 1: amsg = gather(relu(inp)); msg1 = relu(inp + (amsg[b2a]-relu(inp[b2revb]))@W_h)
    gather_sum_kernel<true><<<NATOMS * 32 / 256, 256, 0, stream>>>(inp, a2b, amsg);
    gemm_v2<1, true><<<dim3(2, 2344), 256, 0, stream>>>(
        nullptr, amsg, inp, inp, b2a, b2revb, wh_t,
        msg1, nullptr, nullptr, nullptr, nullptr, nullptr, NBONDS);

    // depth iter 2
    gather_sum_kernel<false><<<NATOMS * 32 / 256, 256, 0, stream>>>(msg1, a2b, amsg);
    gemm_v2<1, false><<<dim3(2, 2344), 256, 0, stream>>>(
        nullptr, amsg, msg1, inp, b2a, b2revb, wh_t,
        msg2, nullptr, nullptr, nullptr, nullptr, nullptr, NBONDS);

    // final aggregation
    gather_sum_kernel<false><<<NATOMS * 32 / 256, 256, 0, stream>>>(msg2, a2b, amsg);

    hipMemsetAsync(mol_acc, 0, (size_t)NMOLS * 2 * 4, stream);

    gemm_v2<2, false><<<dim3(2, 1172), 256, 0, stream>>>(
        f_atoms, amsg, nullptr, nullptr, nullptr, nullptr, wo_t,
        nullptr, b_o, W_ffn, segids, mol_acc, mol_cnt, NATOMS);

    finalize_kernel<<<(NMOLS + 255) / 256, 256, 0, stream>>>(mol_acc, mol_cnt, b_ffn, out);
}